// Round 1
// baseline (763.024 us; speedup 1.0000x reference)
//
#include <hip/hip_runtime.h>
#include <hip/hip_bf16.h>

typedef __bf16 bf16_t;
typedef __bf16 bf16x8 __attribute__((ext_vector_type(8)));
typedef __bf16 bf16x4 __attribute__((ext_vector_type(4)));
typedef float f32x4 __attribute__((ext_vector_type(4)));

#define NE 10
#define DM 512
#define SCALE_F 0.125f

// ---------------- cast fp32 -> bf16 (8 elems/thread) ----------------
__global__ void cast_bf16_kernel(const float* __restrict__ in, bf16_t* __restrict__ out, int n)
{
    const int i = (blockIdx.x * 256 + threadIdx.x) * 8;
    if (i >= n) return;
    float4 a = *(const float4*)(in + i);
    float4 b = *(const float4*)(in + i + 4);
    bf16x8 o;
    o[0] = (bf16_t)a.x; o[1] = (bf16_t)a.y; o[2] = (bf16_t)a.z; o[3] = (bf16_t)a.w;
    o[4] = (bf16_t)b.x; o[5] = (bf16_t)b.y; o[6] = (bf16_t)b.z; o[7] = (bf16_t)b.w;
    *(bf16x8*)(out + i) = o;
}

// ---------------- W[e][k][n] fp32 -> Wt[e][n][k] bf16 ----------------
__global__ void wtrans_kernel(const float* __restrict__ W, bf16_t* __restrict__ Wt)
{
    __shared__ float tile[32][33];
    const int n0 = blockIdx.x * 32, k0 = blockIdx.y * 32, e = blockIdx.z;
    const int tx = threadIdx.x & 31, ty = threadIdx.x >> 5; // ty 0..7
    const float* Wp = W + ((size_t)e * DM + k0) * DM + n0;
#pragma unroll
    for (int r = 0; r < 32; r += 8) tile[ty + r][tx] = Wp[(size_t)(ty + r) * DM + tx];
    __syncthreads();
    bf16_t* Op = Wt + ((size_t)e * DM + n0) * DM + k0;
#pragma unroll
    for (int r = 0; r < 32; r += 8) Op[(size_t)(ty + r) * DM + tx] = (bf16_t)tile[tx][ty + r];
}

// ---------------- gates: softmax over E, top-5, renormalize ----------------
// One 64-thread block per token. Selection on fp32 logits, strict >, lowest index wins ties
// (monotone-equivalent to lax.top_k on softmaxed gates). Softmax denom cancels in renorm.
__global__ void moe_gates(const float* __restrict__ X, const float* __restrict__ gw,
                          const float* __restrict__ gb, float* __restrict__ G)
{
    const int t = blockIdx.x;
    const int lane = threadIdx.x;
    const float* x = X + (size_t)t * DM;
    float p[NE];
#pragma unroll
    for (int e = 0; e < NE; e++) p[e] = 0.f;
    for (int i = lane; i < DM; i += 64) {
        const float xv = x[i];
        const float* g = gw + (size_t)i * NE;
#pragma unroll
        for (int e = 0; e < NE; e++) p[e] += xv * g[e];
    }
#pragma unroll
    for (int off = 32; off > 0; off >>= 1)
#pragma unroll
        for (int e = 0; e < NE; e++) p[e] += __shfl_down(p[e], off);
    if (lane == 0) {
        float l[NE], ex[NE];
        float mx = -3.4e38f;
#pragma unroll
        for (int e = 0; e < NE; e++) { l[e] = p[e] + gb[e]; mx = fmaxf(mx, l[e]); }
#pragma unroll
        for (int e = 0; e < NE; e++) ex[e] = expf(l[e] - mx);
        bool sel[NE];
#pragma unroll
        for (int e = 0; e < NE; e++) sel[e] = false;
        float ssel = 0.f;
        for (int j = 0; j < 5; j++) {
            int bi = 0; float bv = -3.4e38f;
            for (int e = 0; e < NE; e++)
                if (!sel[e] && l[e] > bv) { bv = l[e]; bi = e; }
            sel[bi] = true; ssel += ex[bi];
        }
        const float inv = 1.f / ssel;
        for (int e = 0; e < NE; e++) G[(size_t)t * NE + e] = sel[e] ? ex[e] * inv : 0.f;
    }
}

// ---------------- MoE GEMM: out[t,n] = sum_e g[t,e]*(X[t,:] @ W_e[:,n] + b[e,n]) -----------
// X: [M,512] bf16. Wt: [E][n=512][k=512] bf16 (pre-transposed). 2x2 wave grid; wave tile
// (MF*16) x (NF*16). BM=2*MF*16, BN=2*NF*16. Expert loop with separate acc2, post-scaled by g.
template <typename OutT, bool TRANS, int MF, int NF>
__global__ __launch_bounds__(256, 2)
void moe_gemm(const bf16_t* __restrict__ X, const bf16_t* __restrict__ Wt,
              const float* __restrict__ bias, const float* __restrict__ G,
              OutT* __restrict__ out)
{
    constexpr int BM = 2 * MF * 16;
    constexpr int BN = 2 * NF * 16;
    __shared__ bf16_t As[BM][40];   // pad to 40: 16B-aligned rows, ~2-way banks
    __shared__ bf16_t Bs[BN][40];
    __shared__ float Gs[BM][NE];
    __shared__ float BiasS[NE][BN];

    const int tid = threadIdx.x;
    const int lane = tid & 63, wid = tid >> 6;
    const int wr = wid >> 1, wc = wid & 1;
    const int l15 = lane & 15, quad = lane >> 4;
    const int m0 = blockIdx.x * BM, n0 = blockIdx.y * BN;

    for (int i = tid; i < BM * NE; i += 256) {
        int r = i / NE, e = i - r * NE;
        Gs[r][e] = G[(size_t)(m0 + r) * NE + e];
    }
    for (int i = tid; i < NE * BN; i += 256) {
        int e = i / BN, j = i - e * BN;
        BiasS[e][j] = bias[(size_t)e * DM + n0 + j];
    }

    constexpr int TPRA = 256 / BM;     // threads per A row
    constexpr int EPTA = 32 / TPRA;    // elems per thread
    constexpr int TPRB = 256 / BN;
    constexpr int EPTB = 32 / TPRB;
    const int arow = tid / TPRA, aoff = (tid % TPRA) * EPTA;
    const int brow = tid / TPRB, boff = (tid % TPRB) * EPTB;
    const bf16_t* Xp = X + (size_t)(m0 + arow) * DM + aoff;

    const f32x4 zv = {0.f, 0.f, 0.f, 0.f};
    f32x4 acc[MF][NF];
#pragma unroll
    for (int a = 0; a < MF; a++)
#pragma unroll
        for (int b = 0; b < NF; b++) acc[a][b] = zv;

    for (int e = 0; e < NE; e++) {
        const bf16_t* Wp = Wt + ((size_t)e * DM + n0 + brow) * DM + boff;
        f32x4 acc2[MF][NF];
#pragma unroll
        for (int a = 0; a < MF; a++)
#pragma unroll
            for (int b = 0; b < NF; b++) acc2[a][b] = zv;

        for (int kt = 0; kt < 16; kt++) {
            __syncthreads();
#pragma unroll
            for (int j = 0; j < EPTA; j += 8)
                *(uint4*)(&As[arow][aoff + j]) = *(const uint4*)(Xp + kt * 32 + j);
#pragma unroll
            for (int j = 0; j < EPTB; j += 8)
                *(uint4*)(&Bs[brow][boff + j]) = *(const uint4*)(Wp + kt * 32 + j);
            __syncthreads();
            bf16x8 af[MF], bfr[NF];
#pragma unroll
            for (int mf = 0; mf < MF; mf++)
                af[mf] = *(const bf16x8*)(&As[wr * MF * 16 + mf * 16 + l15][quad * 8]);
#pragma unroll
            for (int nf = 0; nf < NF; nf++)
                bfr[nf] = *(const bf16x8*)(&Bs[wc * NF * 16 + nf * 16 + l15][quad * 8]);
#pragma unroll
            for (int mf = 0; mf < MF; mf++)
#pragma unroll
                for (int nf = 0; nf < NF; nf++)
                    acc2[mf][nf] = __builtin_amdgcn_mfma_f32_16x16x32_bf16(
                        af[mf], bfr[nf], acc2[mf][nf], 0, 0, 0);
        }
#pragma unroll
        for (int mf = 0; mf < MF; mf++)
#pragma unroll
            for (int r = 0; r < 4; r++) {
                const float g = Gs[wr * MF * 16 + mf * 16 + quad * 4 + r][e];
#pragma unroll
                for (int nf = 0; nf < NF; nf++) acc[mf][nf][r] += g * acc2[mf][nf][r];
            }
    }

#pragma unroll
    for (int mf = 0; mf < MF; mf++) {
#pragma unroll
        for (int nf = 0; nf < NF; nf++) {
            const int n = wc * NF * 16 + nf * 16 + l15;
            float vals[4];
#pragma unroll
            for (int r = 0; r < 4; r++) {
                const int m = wr * MF * 16 + mf * 16 + quad * 4 + r;
                float v = acc[mf][nf][r];
#pragma unroll
                for (int e = 0; e < NE; e++) v += Gs[m][e] * BiasS[e][n];
                vals[r] = v;
            }
            if constexpr (TRANS) {
                // out is vpT: [b][o=512][t=4096], write 4 consecutive tokens packed
                const int mg = m0 + wr * MF * 16 + mf * 16 + quad * 4;
                const int b = mg >> 12, t = mg & 4095;
                bf16x4 pk;
                pk[0] = (bf16_t)vals[0]; pk[1] = (bf16_t)vals[1];
                pk[2] = (bf16_t)vals[2]; pk[3] = (bf16_t)vals[3];
                *(bf16x4*)((bf16_t*)out + ((size_t)(b * DM) + n0 + n) * 4096 + t) = pk;
            } else {
#pragma unroll
                for (int r = 0; r < 4; r++) {
                    const int m = wr * MF * 16 + mf * 16 + quad * 4 + r;
                    out[(size_t)(m0 + m) * DM + n0 + n] = (OutT)vals[r];
                }
            }
        }
    }
}

// ---------------- S = scale * Q K^T, written to d_out attn region ----------------
__global__ __launch_bounds__(256, 2)
void attn_s(const bf16_t* __restrict__ qp, const bf16_t* __restrict__ kp,
            float* __restrict__ attn)
{
    __shared__ bf16_t Aq[128][72];
    __shared__ bf16_t Bk[128][72];
    const int kt = blockIdx.x, qt = blockIdx.y, bh = blockIdx.z;
    const int b = bh >> 3, h = bh & 7;
    const int q0 = qt * 128, k0 = kt * 128;
    const int tid = threadIdx.x, lane = tid & 63, wid = tid >> 6;
    const int wr = wid >> 1, wc = wid & 1, l15 = lane & 15, quad = lane >> 4;

    {
        const int row = tid >> 1, off = (tid & 1) * 32;
        const bf16_t* qsrc = qp + (size_t)(b * 512 + q0 + row) * DM + h * 64 + off;
        const bf16_t* ksrc = kp + (size_t)(b * 4096 + k0 + row) * DM + h * 64 + off;
#pragma unroll
        for (int j = 0; j < 32; j += 8) {
            *(uint4*)(&Aq[row][off + j]) = *(const uint4*)(qsrc + j);
            *(uint4*)(&Bk[row][off + j]) = *(const uint4*)(ksrc + j);
        }
    }
    __syncthreads();
    const f32x4 zv = {0.f, 0.f, 0.f, 0.f};
    f32x4 acc[4][4];
#pragma unroll
    for (int a = 0; a < 4; a++)
#pragma unroll
        for (int c = 0; c < 4; c++) acc[a][c] = zv;
#pragma unroll
    for (int ks = 0; ks < 2; ks++) {
        bf16x8 af[4], bfr[4];
#pragma unroll
        for (int mf = 0; mf < 4; mf++)
            af[mf] = *(const bf16x8*)(&Aq[wr * 64 + mf * 16 + l15][ks * 32 + quad * 8]);
#pragma unroll
        for (int nf = 0; nf < 4; nf++)
            bfr[nf] = *(const bf16x8*)(&Bk[wc * 64 + nf * 16 + l15][ks * 32 + quad * 8]);
#pragma unroll
        for (int mf = 0; mf < 4; mf++)
#pragma unroll
            for (int nf = 0; nf < 4; nf++)
                acc[mf][nf] = __builtin_amdgcn_mfma_f32_16x16x32_bf16(
                    af[mf], bfr[nf], acc[mf][nf], 0, 0, 0);
    }
    float* Sp = attn + (size_t)bh * 512 * 4096;
#pragma unroll
    for (int mf = 0; mf < 4; mf++)
#pragma unroll
        for (int r = 0; r < 4; r++) {
            const int m = q0 + wr * 64 + mf * 16 + quad * 4 + r;
#pragma unroll
            for (int nf = 0; nf < 4; nf++) {
                const int n = k0 + wc * 64 + nf * 16 + l15;
                Sp[(size_t)m * 4096 + n] = acc[mf][nf][r] * SCALE_F;
            }
        }
}

// ---------------- row softmax over 4096, in place ----------------
__global__ __launch_bounds__(256)
void softmax_kernel(float* __restrict__ attn)
{
    __shared__ float redm[4], reds[4];
    const int row = blockIdx.x;
    float* p = attn + (size_t)row * 4096;
    const int tid = threadIdx.x;
    float v[16];
    float mx = -3.4e38f;
#pragma unroll
    for (int i = 0; i < 16; i++) { v[i] = p[tid + i * 256]; mx = fmaxf(mx, v[i]); }
#pragma unroll
    for (int off = 32; off > 0; off >>= 1) mx = fmaxf(mx, __shfl_xor(mx, off));
    const int wid = tid >> 6;
    if ((tid & 63) == 0) redm[wid] = mx;
    __syncthreads();
    mx = fmaxf(fmaxf(redm[0], redm[1]), fmaxf(redm[2], redm[3]));
    float s = 0.f;
#pragma unroll
    for (int i = 0; i < 16; i++) { v[i] = __expf(v[i] - mx); s += v[i]; }
#pragma unroll
    for (int off = 32; off > 0; off >>= 1) s += __shfl_xor(s, off);
    if ((tid & 63) == 0) reds[wid] = s;
    __syncthreads();
    s = reds[0] + reds[1] + reds[2] + reds[3];
    const float inv = 1.f / s;
#pragma unroll
    for (int i = 0; i < 16; i++) p[tid + i * 256] = v[i] * inv;
}

// ---------------- PV: x[b,q,h*64+n] += sum_k attn[bh,q,k]*v[k,n], K-split w/ atomics ------
__global__ __launch_bounds__(256, 2)
void attn_pv(const float* __restrict__ attn, const bf16_t* __restrict__ vpT,
             float* __restrict__ x)
{
    __shared__ bf16_t Ap[64][72];
    __shared__ bf16_t Bv[64][72];
    const int ks = blockIdx.x, qt = blockIdx.y, bh = blockIdx.z;
    const int b = bh >> 3, h = bh & 7;
    const int q0 = qt * 64;
    const int tid = threadIdx.x, lane = tid & 63, wid = tid >> 6;
    const int l15 = lane & 15, quad = lane >> 4;
    const int wm0 = wid * 16;

    const f32x4 zv = {0.f, 0.f, 0.f, 0.f};
    f32x4 acc[4];
#pragma unroll
    for (int nf = 0; nf < 4; nf++) acc[nf] = zv;

    const int row = tid >> 2, off = (tid & 3) * 16;
    const float* asrc = attn + ((size_t)bh * 512 + q0 + row) * 4096 + off;
    const bf16_t* vsrc = vpT + ((size_t)(b * DM + h * 64 + row)) * 4096 + off;

    for (int kb = 0; kb < 16; kb++) {
        const int kbase = ks * 1024 + kb * 64;
        __syncthreads();
        float4 f0 = *(const float4*)(asrc + kbase);
        float4 f1 = *(const float4*)(asrc + kbase + 4);
        float4 f2 = *(const float4*)(asrc + kbase + 8);
        float4 f3 = *(const float4*)(asrc + kbase + 12);
        bf16x8 o0, o1;
        o0[0] = (bf16_t)f0.x; o0[1] = (bf16_t)f0.y; o0[2] = (bf16_t)f0.z; o0[3] = (bf16_t)f0.w;
        o0[4] = (bf16_t)f1.x; o0[5] = (bf16_t)f1.y; o0[6] = (bf16_t)f1.z; o0[7] = (bf16_t)f1.w;
        o1[0] = (bf16_t)f2.x; o1[1] = (bf16_t)f2.y; o1[2] = (bf16_t)f2.z; o1[3] = (bf16_t)f2.w;
        o1[4] = (bf16_t)f3.x; o1[5] = (bf16_t)f3.y; o1[6] = (bf16_t)f3.z; o1[7] = (bf16_t)f3.w;
        *(bf16x8*)(&Ap[row][off]) = o0;
        *(bf16x8*)(&Ap[row][off + 8]) = o1;
        *(uint4*)(&Bv[row][off]) = *(const uint4*)(vsrc + kbase);
        *(uint4*)(&Bv[row][off + 8]) = *(const uint4*)(vsrc + kbase + 8);
        __syncthreads();
#pragma unroll
        for (int kss = 0; kss < 2; kss++) {
            bf16x8 af = *(const bf16x8*)(&Ap[wm0 + l15][kss * 32 + quad * 8]);
#pragma unroll
            for (int nf = 0; nf < 4; nf++) {
                bf16x8 bfr = *(const bf16x8*)(&Bv[nf * 16 + l15][kss * 32 + quad * 8]);
                acc[nf] = __builtin_amdgcn_mfma_f32_16x16x32_bf16(af, bfr, acc[nf], 0, 0, 0);
            }
        }
    }
#pragma unroll
    for (int nf = 0; nf < 4; nf++) {
        const int n = nf * 16 + l15;
#pragma unroll
        for (int r = 0; r < 4; r++) {
            const int m = wm0 + quad * 4 + r;
            atomicAdd(&x[(size_t)(b * 512 + q0 + m) * DM + h * 64 + n], acc[nf][r]);
        }
    }
}

// ---------------- host ----------------
extern "C" void kernel_launch(void* const* d_in, const int* in_sizes, int n_in,
                              void* d_out, int out_size, void* d_ws, size_t ws_size,
                              hipStream_t stream)
{
    (void)in_sizes; (void)n_in; (void)out_size; (void)ws_size;
    const float* q    = (const float*)d_in[0];
    const float* kv   = (const float*)d_in[1];
    const float* q_gw = (const float*)d_in[2];
    const float* q_gb = (const float*)d_in[3];
    const float* q_w  = (const float*)d_in[4];
    const float* q_b  = (const float*)d_in[5];
    const float* k_gw = (const float*)d_in[6];
    const float* k_gb = (const float*)d_in[7];
    const float* k_w  = (const float*)d_in[8];
    const float* k_b  = (const float*)d_in[9];
    const float* v_gw = (const float*)d_in[10];
    const float* v_gb = (const float*)d_in[11];
    const float* v_w  = (const float*)d_in[12];
    const float* v_b  = (const float*)d_in[13];
    const float* o_gw = (const float*)d_in[14];
    const float* o_gb = (const float*)d_in[15];
    const float* o_w  = (const float*)d_in[16];
    const float* o_b  = (const float*)d_in[17];

    float* out0 = (float*)d_out;
    float* attn = out0 + (size_t)1024 * 512;

    char* ws = (char*)d_ws;
    size_t off = 0;
    auto alloc = [&](size_t bytes) {
        void* p = ws + off;
        off += (bytes + 255) & ~(size_t)255;
        return p;
    };
    bf16_t* Xq   = (bf16_t*)alloc((size_t)1024 * 512 * 2);
    bf16_t* Xkv  = (bf16_t*)alloc((size_t)8192 * 512 * 2);
    bf16_t* Wq_t = (bf16_t*)alloc((size_t)NE * 512 * 512 * 2);
    bf16_t* Wk_t = (bf16_t*)alloc((size_t)NE * 512 * 512 * 2);
    bf16_t* Wv_t = (bf16_t*)alloc((size_t)NE * 512 * 512 * 2);
    bf16_t* Wo_t = (bf16_t*)alloc((size_t)NE * 512 * 512 * 2);
    bf16_t* qp   = (bf16_t*)alloc((size_t)1024 * 512 * 2);
    bf16_t* kp   = (bf16_t*)alloc((size_t)8192 * 512 * 2);
    bf16_t* vpT  = (bf16_t*)alloc((size_t)8192 * 512 * 2);
    float*  xatt = (float*)alloc((size_t)1024 * 512 * 4);
    bf16_t* xbf  = (bf16_t*)alloc((size_t)1024 * 512 * 2);
    float*  Gq   = (float*)alloc((size_t)1024 * NE * 4);
    float*  Gk   = (float*)alloc((size_t)8192 * NE * 4);
    float*  Gv   = (float*)alloc((size_t)8192 * NE * 4);
    float*  Go   = (float*)alloc((size_t)1024 * NE * 4);

    cast_bf16_kernel<<<256, 256, 0, stream>>>(q, Xq, 1024 * 512);
    cast_bf16_kernel<<<2048, 256, 0, stream>>>(kv, Xkv, 8192 * 512);
    dim3 wt(16, 16, NE);
    wtrans_kernel<<<wt, 256, 0, stream>>>(q_w, Wq_t);
    wtrans_kernel<<<wt, 256, 0, stream>>>(k_w, Wk_t);
    wtrans_kernel<<<wt, 256, 0, stream>>>(v_w, Wv_t);
    wtrans_kernel<<<wt, 256, 0, stream>>>(o_w, Wo_t);
    moe_gates<<<1024, 64, 0, stream>>>(q, q_gw, q_gb, Gq);
    moe_gates<<<8192, 64, 0, stream>>>(kv, k_gw, k_gb, Gk);
    moe_gates<<<8192, 64, 0, stream>>>(kv, v_gw, v_gb, Gv);

    moe_gemm<bf16_t, false, 2, 2><<<dim3(16, 8), 256, 0, stream>>>(Xq, Wq_t, q_b, Gq, qp);
    moe_gemm<bf16_t, false, 4, 2><<<dim3(64, 8), 256, 0, stream>>>(Xkv, Wk_t, k_b, Gk, kp);
    moe_gemm<bf16_t, true,  4, 2><<<dim3(64, 8), 256, 0, stream>>>(Xkv, Wv_t, v_b, Gv, vpT);

    attn_s<<<dim3(32, 4, 16), 256, 0, stream>>>(qp, kp, attn);
    softmax_kernel<<<8192, 256, 0, stream>>>(attn);
    hipMemsetAsync(xatt, 0, (size_t)1024 * 512 * 4, stream);
    attn_pv<<<dim3(4, 8, 16), 256, 0, stream>>>(attn, vpT, xatt);

    moe_gates<<<1024, 64, 0, stream>>>(xatt, o_gw, o_gb, Go);
    cast_bf16_kernel<<<256, 256, 0, stream>>>(xatt, xbf, 1024 * 512);
    moe_gemm<float, false, 2, 2><<<dim3(16, 8), 256, 0, stream>>>(xbf, Wo_t, o_b, Go, out0);
}

// Round 2
// 596.868 us; speedup vs baseline: 1.2784x; 1.2784x over previous
//
#include <hip/hip_runtime.h>
#include <hip/hip_bf16.h>

typedef __bf16 bf16_t;
typedef __bf16 bf16x8 __attribute__((ext_vector_type(8)));
typedef __bf16 bf16x4 __attribute__((ext_vector_type(4)));
typedef float f32x4 __attribute__((ext_vector_type(4)));

#define NE 10
#define DM 512
#define SCALE_F 0.125f

// async global->LDS, 16B per lane. LDS dst is wave-uniform base + lane*16.
__device__ __forceinline__ void gl16(const void* g, void* l) {
    __builtin_amdgcn_global_load_lds(
        (const __attribute__((address_space(1))) unsigned int*)g,
        (__attribute__((address_space(3))) unsigned int*)l, 16, 0, 0);
}

// ---------------- cast fp32 -> bf16 (8 elems/thread) ----------------
__global__ void cast_bf16_kernel(const float* __restrict__ in, bf16_t* __restrict__ out, int n)
{
    const int i = (blockIdx.x * 256 + threadIdx.x) * 8;
    if (i >= n) return;
    float4 a = *(const float4*)(in + i);
    float4 b = *(const float4*)(in + i + 4);
    bf16x8 o;
    o[0] = (bf16_t)a.x; o[1] = (bf16_t)a.y; o[2] = (bf16_t)a.z; o[3] = (bf16_t)a.w;
    o[4] = (bf16_t)b.x; o[5] = (bf16_t)b.y; o[6] = (bf16_t)b.z; o[7] = (bf16_t)b.w;
    *(bf16x8*)(out + i) = o;
}

// ---------------- 4x W[e][k][n] fp32 -> Wt[which][e][n][k] bf16 (fused) ----------------
__global__ void wtrans4_kernel(const float* __restrict__ W0, const float* __restrict__ W1,
                               const float* __restrict__ W2, const float* __restrict__ W3,
                               bf16_t* __restrict__ Wt)
{
    __shared__ float tile[32][33];
    const int z = blockIdx.z, which = z / NE, e = z - which * NE;
    const float* W = which == 0 ? W0 : which == 1 ? W1 : which == 2 ? W2 : W3;
    const int n0 = blockIdx.x * 32, k0 = blockIdx.y * 32;
    const int tx = threadIdx.x & 31, ty = threadIdx.x >> 5; // ty 0..7
    const float* Wp = W + ((size_t)e * DM + k0) * DM + n0;
#pragma unroll
    for (int r = 0; r < 32; r += 8) tile[ty + r][tx] = Wp[(size_t)(ty + r) * DM + tx];
    __syncthreads();
    bf16_t* Op = Wt + (((size_t)which * NE + e) * DM + n0) * DM + k0;
#pragma unroll
    for (int r = 0; r < 32; r += 8) Op[(size_t)(ty + r) * DM + tx] = (bf16_t)tile[tx][ty + r];
}

// ---------------- top-k gate selection + renorm (fp32, matches lax.top_k ties) ----------
__device__ __forceinline__ void topk_write(const float* p, const float* __restrict__ gb,
                                           float* __restrict__ G, int t)
{
    float l[NE], ex[NE];
    float mx = -3.4e38f;
#pragma unroll
    for (int e = 0; e < NE; e++) { l[e] = p[e] + gb[e]; mx = fmaxf(mx, l[e]); }
#pragma unroll
    for (int e = 0; e < NE; e++) ex[e] = __expf(l[e] - mx);
    bool sel[NE];
#pragma unroll
    for (int e = 0; e < NE; e++) sel[e] = false;
    float ssel = 0.f;
    for (int j = 0; j < 5; j++) {
        int bi = 0; float bv = -3.4e38f;
        for (int e = 0; e < NE; e++)
            if (!sel[e] && l[e] > bv) { bv = l[e]; bi = e; }
        sel[bi] = true; ssel += ex[bi];
    }
    const float inv = 1.f / ssel;
    for (int e = 0; e < NE; e++) G[(size_t)t * NE + e] = sel[e] ? ex[e] * inv : 0.f;
}

// one 64-thread block per token
__global__ void moe_gates(const float* __restrict__ X, const float* __restrict__ gw,
                          const float* __restrict__ gb, float* __restrict__ G)
{
    const int t = blockIdx.x;
    const int lane = threadIdx.x;
    const float* x = X + (size_t)t * DM;
    float p[NE];
#pragma unroll
    for (int e = 0; e < NE; e++) p[e] = 0.f;
    for (int i = lane; i < DM; i += 64) {
        const float xv = x[i];
        const float* g = gw + (size_t)i * NE;
#pragma unroll
        for (int e = 0; e < NE; e++) p[e] += xv * g[e];
    }
#pragma unroll
    for (int off = 32; off > 0; off >>= 1)
#pragma unroll
        for (int e = 0; e < NE; e++) p[e] += __shfl_down(p[e], off);
    if (lane == 0) topk_write(p, gb, G, t);
}

// fused k+v gates: 4 waves/block, one token per wave, X read once
__global__ void moe_gates_kv(const float* __restrict__ X,
                             const float* __restrict__ kgw, const float* __restrict__ kgb,
                             const float* __restrict__ vgw, const float* __restrict__ vgb,
                             float* __restrict__ Gk, float* __restrict__ Gv)
{
    const int t = blockIdx.x * 4 + (threadIdx.x >> 6);
    const int lane = threadIdx.x & 63;
    const float* x = X + (size_t)t * DM;
    float xr[8];
    *(float4*)&xr[0] = *(const float4*)(x + lane * 8);
    *(float4*)&xr[4] = *(const float4*)(x + lane * 8 + 4);
    float pk[NE], pv[NE];
#pragma unroll
    for (int e = 0; e < NE; e++) { pk[e] = 0.f; pv[e] = 0.f; }
#pragma unroll
    for (int j = 0; j < 8; j++) {
        const int i = lane * 8 + j;
        const float* gk = kgw + (size_t)i * NE;
        const float* gv = vgw + (size_t)i * NE;
#pragma unroll
        for (int e = 0; e < NE; e++) { pk[e] += xr[j] * gk[e]; pv[e] += xr[j] * gv[e]; }
    }
#pragma unroll
    for (int off = 32; off > 0; off >>= 1)
#pragma unroll
        for (int e = 0; e < NE; e++) { pk[e] += __shfl_down(pk[e], off); pv[e] += __shfl_down(pv[e], off); }
    if (lane == 0) { topk_write(pk, kgb, Gk, t); topk_write(pv, vgb, Gv, t); }
}

// ---------------- MoE GEMM v2: async staging, XOR-swizzled LDS, BK=64 ----------------
// out[t,n] = sum_e g[t,e]*(X[t,:] @ W_e[:,n] + b[e,n]).  Wt: [E][n][k] bf16.
// LDS layout: row r (BK=64 bf16 = 8 chunks of 16B); chunk position p holds source
// chunk p ^ (r&7) -> ds_read_b128 hits the 8-access/bank floor; staging is pure
// global_load_lds (no ds_write), swizzle realized by permuting per-lane global addrs.
template <typename OutT, bool TRANS, int MF, int NF>
__global__ __launch_bounds__(256, 2)
void moe_gemm(const bf16_t* __restrict__ X, const bf16_t* __restrict__ Wt,
              const float* __restrict__ bias, const float* __restrict__ G,
              OutT* __restrict__ out)
{
    constexpr int BM = 2 * MF * 16;
    constexpr int BN = 2 * NF * 16;  // 64
    constexpr int BK = 64;
    __shared__ bf16_t As[BM * BK];
    __shared__ bf16_t Bs[BN * BK];
    __shared__ float Gs[BM][NE];
    __shared__ float BiasS[NE][BN];

    const int tid = threadIdx.x, lane = tid & 63, w = tid >> 6;
    const int wr = w >> 1, wc = w & 1;
    const int l15 = lane & 15, quad = lane >> 4;
    const int m0 = blockIdx.x * BM, n0 = blockIdx.y * BN;

    for (int i = tid; i < BM * NE; i += 256) {
        int r = i / NE, e = i - r * NE;
        Gs[r][e] = G[(size_t)(m0 + r) * NE + e];
    }
    for (int i = tid; i < NE * BN; i += 256) {
        int e = i / BN, j = i - e * BN;
        BiasS[e][j] = bias[(size_t)e * DM + n0 + j];
    }

    // staging geometry: one call = 64 lanes x 16B = 8 rows x 128B
    const int rsub = lane >> 3, pch = lane & 7;
    const int csw = pch ^ rsub;             // swizzled source chunk
    constexpr int AC = BM / 32;             // A calls per wave
    const bf16_t* aptr[AC];
    bf16_t* alds[AC];
#pragma unroll
    for (int j = 0; j < AC; j++) {
        const int rb = w * (BM / 4) + j * 8;
        aptr[j] = X + (size_t)(m0 + rb + rsub) * DM + csw * 8;
        alds[j] = (bf16_t*)As + rb * BK;
    }
    bf16_t* blds[2];
#pragma unroll
    for (int j = 0; j < 2; j++) blds[j] = (bf16_t*)Bs + (w * 16 + j * 8) * BK;

    int amr[MF], bnr[NF];
#pragma unroll
    for (int mf = 0; mf < MF; mf++) amr[mf] = wr * MF * 16 + mf * 16 + l15;
#pragma unroll
    for (int nf = 0; nf < NF; nf++) bnr[nf] = wc * NF * 16 + nf * 16 + l15;

    const f32x4 zv = {0.f, 0.f, 0.f, 0.f};
    f32x4 acc[MF][NF];
#pragma unroll
    for (int a = 0; a < MF; a++)
#pragma unroll
        for (int b = 0; b < NF; b++) acc[a][b] = zv;

    for (int e = 0; e < NE; e++) {
        const bf16_t* bbase = Wt + ((size_t)e * DM + n0 + w * 16 + rsub) * DM + csw * 8;
        f32x4 acc2[MF][NF];
#pragma unroll
        for (int a = 0; a < MF; a++)
#pragma unroll
            for (int b = 0; b < NF; b++) acc2[a][b] = zv;

        for (int kt = 0; kt < 8; kt++) {
            __syncthreads();
#pragma unroll
            for (int j = 0; j < AC; j++) gl16(aptr[j] + kt * BK, alds[j]);
#pragma unroll
            for (int j = 0; j < 2; j++) gl16(bbase + (size_t)j * 8 * DM + kt * BK, blds[j]);
            __syncthreads();
            bf16x8 af[2][MF], bfr[2][NF];
#pragma unroll
            for (int ks = 0; ks < 2; ks++) {
#pragma unroll
                for (int mf = 0; mf < MF; mf++)
                    af[ks][mf] = *(const bf16x8*)(As + amr[mf] * BK + (((ks << 2) | quad) ^ (amr[mf] & 7)) * 8);
#pragma unroll
                for (int nf = 0; nf < NF; nf++)
                    bfr[ks][nf] = *(const bf16x8*)(Bs + bnr[nf] * BK + (((ks << 2) | quad) ^ (bnr[nf] & 7)) * 8);
            }
#pragma unroll
            for (int ks = 0; ks < 2; ks++)
#pragma unroll
                for (int mf = 0; mf < MF; mf++)
#pragma unroll
                    for (int nf = 0; nf < NF; nf++)
                        acc2[mf][nf] = __builtin_amdgcn_mfma_f32_16x16x32_bf16(
                            af[ks][mf], bfr[ks][nf], acc2[mf][nf], 0, 0, 0);
        }
#pragma unroll
        for (int mf = 0; mf < MF; mf++)
#pragma unroll
            for (int r = 0; r < 4; r++) {
                const float g = Gs[wr * MF * 16 + mf * 16 + quad * 4 + r][e];
#pragma unroll
                for (int nf = 0; nf < NF; nf++) acc[mf][nf][r] += g * acc2[mf][nf][r];
            }
    }

#pragma unroll
    for (int mf = 0; mf < MF; mf++) {
#pragma unroll
        for (int nf = 0; nf < NF; nf++) {
            const int n = wc * NF * 16 + nf * 16 + l15;
            float vals[4];
#pragma unroll
            for (int r = 0; r < 4; r++) {
                const int m = wr * MF * 16 + mf * 16 + quad * 4 + r;
                float v = acc[mf][nf][r];
#pragma unroll
                for (int e = 0; e < NE; e++) v += Gs[m][e] * BiasS[e][n];
                vals[r] = v;
            }
            if constexpr (TRANS) {
                const int mg = m0 + wr * MF * 16 + mf * 16 + quad * 4;
                const int b = mg >> 12, t = mg & 4095;
                bf16x4 pk;
                pk[0] = (bf16_t)vals[0]; pk[1] = (bf16_t)vals[1];
                pk[2] = (bf16_t)vals[2]; pk[3] = (bf16_t)vals[3];
                *(bf16x4*)((bf16_t*)out + ((size_t)(b * DM) + n0 + n) * 4096 + t) = pk;
            } else {
#pragma unroll
                for (int r = 0; r < 4; r++) {
                    const int m = wr * MF * 16 + mf * 16 + quad * 4 + r;
                    out[(size_t)(m0 + m) * DM + n0 + n] = (OutT)vals[r];
                }
            }
        }
    }
}

// ---------------- S = scale * Q K^T -> d_out attn region ----------------
__global__ __launch_bounds__(256, 2)
void attn_s(const bf16_t* __restrict__ qp, const bf16_t* __restrict__ kp,
            float* __restrict__ attn)
{
    __shared__ bf16_t Aq[128][72];
    __shared__ bf16_t Bk[128][72];
    const int kt = blockIdx.x, qt = blockIdx.y, bh = blockIdx.z;
    const int b = bh >> 3, h = bh & 7;
    const int q0 = qt * 128, k0 = kt * 128;
    const int tid = threadIdx.x, lane = tid & 63, wid = tid >> 6;
    const int wr = wid >> 1, wc = wid & 1, l15 = lane & 15, quad = lane >> 4;

    {
        const int row = tid >> 1, off = (tid & 1) * 32;
        const bf16_t* qsrc = qp + (size_t)(b * 512 + q0 + row) * DM + h * 64 + off;
        const bf16_t* ksrc = kp + (size_t)(b * 4096 + k0 + row) * DM + h * 64 + off;
#pragma unroll
        for (int j = 0; j < 32; j += 8) {
            *(uint4*)(&Aq[row][off + j]) = *(const uint4*)(qsrc + j);
            *(uint4*)(&Bk[row][off + j]) = *(const uint4*)(ksrc + j);
        }
    }
    __syncthreads();
    const f32x4 zv = {0.f, 0.f, 0.f, 0.f};
    f32x4 acc[4][4];
#pragma unroll
    for (int a = 0; a < 4; a++)
#pragma unroll
        for (int c = 0; c < 4; c++) acc[a][c] = zv;
#pragma unroll
    for (int ks = 0; ks < 2; ks++) {
        bf16x8 af[4], bfr[4];
#pragma unroll
        for (int mf = 0; mf < 4; mf++)
            af[mf] = *(const bf16x8*)(&Aq[wr * 64 + mf * 16 + l15][ks * 32 + quad * 8]);
#pragma unroll
        for (int nf = 0; nf < 4; nf++)
            bfr[nf] = *(const bf16x8*)(&Bk[wc * 64 + nf * 16 + l15][ks * 32 + quad * 8]);
#pragma unroll
        for (int mf = 0; mf < 4; mf++)
#pragma unroll
            for (int nf = 0; nf < 4; nf++)
                acc[mf][nf] = __builtin_amdgcn_mfma_f32_16x16x32_bf16(
                    af[mf], bfr[nf], acc[mf][nf], 0, 0, 0);
    }
    float* Sp = attn + (size_t)bh * 512 * 4096;
#pragma unroll
    for (int mf = 0; mf < 4; mf++)
#pragma unroll
        for (int r = 0; r < 4; r++) {
            const int m = q0 + wr * 64 + mf * 16 + quad * 4 + r;
#pragma unroll
            for (int nf = 0; nf < 4; nf++) {
                const int n = k0 + wc * 64 + nf * 16 + l15;
                Sp[(size_t)m * 4096 + n] = acc[mf][nf][r] * SCALE_F;
            }
        }
}

// ---------------- row softmax over 4096, in place, thread-consecutive float4 ----------
__global__ __launch_bounds__(256)
void softmax_kernel(float* __restrict__ attn)
{
    __shared__ float redm[4], reds[4];
    float* p = attn + (size_t)blockIdx.x * 4096 + threadIdx.x * 16;
    const int tid = threadIdx.x;
    float v[16];
#pragma unroll
    for (int i = 0; i < 4; i++) *(float4*)&v[i * 4] = *(const float4*)(p + i * 4);
    float mx = -3.4e38f;
#pragma unroll
    for (int i = 0; i < 16; i++) mx = fmaxf(mx, v[i]);
#pragma unroll
    for (int off = 32; off > 0; off >>= 1) mx = fmaxf(mx, __shfl_xor(mx, off));
    const int wid = tid >> 6;
    if ((tid & 63) == 0) redm[wid] = mx;
    __syncthreads();
    mx = fmaxf(fmaxf(redm[0], redm[1]), fmaxf(redm[2], redm[3]));
    float s = 0.f;
#pragma unroll
    for (int i = 0; i < 16; i++) { v[i] = __expf(v[i] - mx); s += v[i]; }
#pragma unroll
    for (int off = 32; off > 0; off >>= 1) s += __shfl_xor(s, off);
    if ((tid & 63) == 0) reds[wid] = s;
    __syncthreads();
    s = reds[0] + reds[1] + reds[2] + reds[3];
    const float inv = 1.f / s;
#pragma unroll
    for (int i = 0; i < 16; i++) v[i] *= inv;
#pragma unroll
    for (int i = 0; i < 4; i++) *(float4*)(p + i * 4) = *(const float4*)&v[i * 4];
}

// ---------------- PV: x[b,q,h*64+n] += sum_k attn[bh,q,k]*v[n,k], K-split 4, BK=64 -----
__global__ __launch_bounds__(256, 2)
void attn_pv(const float* __restrict__ attn, const bf16_t* __restrict__ vpT,
             float* __restrict__ x)
{
    __shared__ bf16_t Ap[64][72];   // manual staging (fp32->bf16 cvt), padded
    __shared__ bf16_t Bv[64 * 64];  // async staging, swizzled
    const int ksp = blockIdx.x, qt = blockIdx.y, bh = blockIdx.z;
    const int b = bh >> 3, h = bh & 7;
    const int q0 = qt * 64;
    const int tid = threadIdx.x, lane = tid & 63, w = tid >> 6;
    const int wr = w >> 1, wc = w & 1, l15 = lane & 15, quad = lane >> 4;

    const int rsub = lane >> 3, pch = lane & 7, csw = pch ^ rsub;
    const bf16_t* bptr[2];
    bf16_t* blds[2];
#pragma unroll
    for (int j = 0; j < 2; j++) {
        const int rb = w * 16 + j * 8;
        bptr[j] = vpT + ((size_t)(b * DM + h * 64 + rb + rsub)) * 4096 + ksp * 1024 + csw * 8;
        blds[j] = (bf16_t*)Bv + rb * 64;
    }
    const int arow = tid >> 2, aoff = (tid & 3) * 16;
    const float* asrc = attn + ((size_t)(bh * 512) + q0 + arow) * 4096 + ksp * 1024 + aoff;

    const f32x4 zv = {0.f, 0.f, 0.f, 0.f};
    f32x4 acc[2][2];
#pragma unroll
    for (int a = 0; a < 2; a++)
#pragma unroll
        for (int c = 0; c < 2; c++) acc[a][c] = zv;
    const int amr[2] = {wr * 32 + l15, wr * 32 + 16 + l15};
    const int bnr[2] = {wc * 32 + l15, wc * 32 + 16 + l15};

    for (int kt = 0; kt < 16; kt++) {
        __syncthreads();
#pragma unroll
        for (int j = 0; j < 2; j++) gl16(bptr[j] + kt * 64, blds[j]);
        float4 f0 = *(const float4*)(asrc + kt * 64);
        float4 f1 = *(const float4*)(asrc + kt * 64 + 4);
        float4 f2 = *(const float4*)(asrc + kt * 64 + 8);
        float4 f3 = *(const float4*)(asrc + kt * 64 + 12);
        bf16x8 o0, o1;
        o0[0] = (bf16_t)f0.x; o0[1] = (bf16_t)f0.y; o0[2] = (bf16_t)f0.z; o0[3] = (bf16_t)f0.w;
        o0[4] = (bf16_t)f1.x; o0[5] = (bf16_t)f1.y; o0[6] = (bf16_t)f1.z; o0[7] = (bf16_t)f1.w;
        o1[0] = (bf16_t)f2.x; o1[1] = (bf16_t)f2.y; o1[2] = (bf16_t)f2.z; o1[3] = (bf16_t)f2.w;
        o1[4] = (bf16_t)f3.x; o1[5] = (bf16_t)f3.y; o1[6] = (bf16_t)f3.z; o1[7] = (bf16_t)f3.w;
        *(bf16x8*)(&Ap[arow][aoff]) = o0;
        *(bf16x8*)(&Ap[arow][aoff + 8]) = o1;
        __syncthreads();
        bf16x8 af[2][2], bfr[2][2];
#pragma unroll
        for (int ks = 0; ks < 2; ks++) {
#pragma unroll
            for (int mf = 0; mf < 2; mf++)
                af[ks][mf] = *(const bf16x8*)(&Ap[amr[mf]][ks * 32 + quad * 8]);
#pragma unroll
            for (int nf = 0; nf < 2; nf++)
                bfr[ks][nf] = *(const bf16x8*)(Bv + bnr[nf] * 64 + (((ks << 2) | quad) ^ (bnr[nf] & 7)) * 8);
        }
#pragma unroll
        for (int ks = 0; ks < 2; ks++)
#pragma unroll
            for (int mf = 0; mf < 2; mf++)
#pragma unroll
                for (int nf = 0; nf < 2; nf++)
                    acc[mf][nf] = __builtin_amdgcn_mfma_f32_16x16x32_bf16(
                        af[ks][mf], bfr[ks][nf], acc[mf][nf], 0, 0, 0);
    }
#pragma unroll
    for (int mf = 0; mf < 2; mf++)
#pragma unroll
        for (int nf = 0; nf < 2; nf++) {
            const int n = wc * 32 + nf * 16 + l15;
#pragma unroll
            for (int r = 0; r < 4; r++) {
                const int m = wr * 32 + mf * 16 + quad * 4 + r;
                atomicAdd(&x[(size_t)(b * 512 + q0 + m) * DM + h * 64 + n], acc[mf][nf][r]);
            }
        }
}

// ---------------- host ----------------
extern "C" void kernel_launch(void* const* d_in, const int* in_sizes, int n_in,
                              void* d_out, int out_size, void* d_ws, size_t ws_size,
                              hipStream_t stream)
{
    (void)in_sizes; (void)n_in; (void)out_size; (void)ws_size;
    const float* q    = (const float*)d_in[0];
    const float* kv   = (const float*)d_in[1];
    const float* q_gw = (const float*)d_in[2];
    const float* q_gb = (const float*)d_in[3];
    const float* q_w  = (const float*)d_in[4];
    const float* q_b  = (const float*)d_in[5];
    const float* k_gw = (const float*)d_in[6];
    const float* k_gb = (const float*)d_in[7];
    const float* k_w  = (const float*)d_in[8];
    const float* k_b  = (const float*)d_in[9];
    const float* v_gw = (const float*)d_in[10];
    const float* v_gb = (const float*)d_in[11];
    const float* v_w  = (const float*)d_in[12];
    const float* v_b  = (const float*)d_in[13];
    const float* o_gw = (const float*)d_in[14];
    const float* o_gb = (const float*)d_in[15];
    const float* o_w  = (const float*)d_in[16];
    const float* o_b  = (const float*)d_in[17];

    float* out0 = (float*)d_out;
    float* attn = out0 + (size_t)1024 * 512;

    char* ws = (char*)d_ws;
    size_t off = 0;
    auto alloc = [&](size_t bytes) {
        void* p = ws + off;
        off += (bytes + 255) & ~(size_t)255;
        return p;
    };
    bf16_t* Xq   = (bf16_t*)alloc((size_t)1024 * 512 * 2);
    bf16_t* Xkv  = (bf16_t*)alloc((size_t)8192 * 512 * 2);
    bf16_t* Wall = (bf16_t*)alloc((size_t)4 * NE * 512 * 512 * 2); // q,k,v,o transposed
    bf16_t* Wq_t = Wall;
    bf16_t* Wk_t = Wall + (size_t)1 * NE * 512 * 512;
    bf16_t* Wv_t = Wall + (size_t)2 * NE * 512 * 512;
    bf16_t* Wo_t = Wall + (size_t)3 * NE * 512 * 512;
    bf16_t* qp   = (bf16_t*)alloc((size_t)1024 * 512 * 2);
    bf16_t* kp   = (bf16_t*)alloc((size_t)8192 * 512 * 2);
    bf16_t* vpT  = (bf16_t*)alloc((size_t)8192 * 512 * 2);
    float*  xatt = (float*)alloc((size_t)1024 * 512 * 4);
    bf16_t* xbf  = (bf16_t*)alloc((size_t)1024 * 512 * 2);
    float*  Gq   = (float*)alloc((size_t)1024 * NE * 4);
    float*  Gk   = (float*)alloc((size_t)8192 * NE * 4);
    float*  Gv   = (float*)alloc((size_t)8192 * NE * 4);
    float*  Go   = (float*)alloc((size_t)1024 * NE * 4);

    cast_bf16_kernel<<<256, 256, 0, stream>>>(q, Xq, 1024 * 512);
    cast_bf16_kernel<<<2048, 256, 0, stream>>>(kv, Xkv, 8192 * 512);
    wtrans4_kernel<<<dim3(16, 16, 4 * NE), 256, 0, stream>>>(q_w, k_w, v_w, o_w, Wall);
    moe_gates<<<1024, 64, 0, stream>>>(q, q_gw, q_gb, Gq);
    moe_gates_kv<<<2048, 256, 0, stream>>>(kv, k_gw, k_gb, v_gw, v_gb, Gk, Gv);

    moe_gemm<bf16_t, false, 2, 2><<<dim3(16, 8), 256, 0, stream>>>(Xq, Wq_t, q_b, Gq, qp);
    moe_gemm<bf16_t, false, 4, 2><<<dim3(64, 8), 256, 0, stream>>>(Xkv, Wk_t, k_b, Gk, kp);
    moe_gemm<bf16_t, true,  4, 2><<<dim3(64, 8), 256, 0, stream>>>(Xkv, Wv_t, v_b, Gv, vpT);

    attn_s<<<dim3(32, 4, 16), 256, 0, stream>>>(qp, kp, attn);
    softmax_kernel<<<8192, 256, 0, stream>>>(attn);
    hipMemsetAsync(xatt, 0, (size_t)1024 * 512 * 4, stream);
    attn_pv<<<dim3(4, 8, 16), 256, 0, stream>>>(attn, vpT, xatt);

    moe_gates<<<1024, 64, 0, stream>>>(xatt, o_gw, o_gb, Go);
    cast_bf16_kernel<<<256, 256, 0, stream>>>(xatt, xbf, 1024 * 512);
    moe_gemm<float, false, 2, 2><<<dim3(16, 8), 256, 0, stream>>>(xbf, Wo_t, o_b, Go, out0);
}

// Round 3
// 470.905 us; speedup vs baseline: 1.6203x; 1.2675x over previous
//
#include <hip/hip_runtime.h>
#include <hip/hip_bf16.h>

typedef __bf16 bf16_t;
typedef __bf16 bf16x8 __attribute__((ext_vector_type(8)));
typedef __bf16 bf16x4 __attribute__((ext_vector_type(4)));
typedef float f32x4 __attribute__((ext_vector_type(4)));

#define NE 10
#define DM 512
#define SCALE_F 0.125f

// async global->LDS, 16B per lane. LDS dst is wave-uniform base + lane*16.
__device__ __forceinline__ void gl16(const void* g, void* l) {
    __builtin_amdgcn_global_load_lds(
        (const __attribute__((address_space(1))) unsigned int*)g,
        (__attribute__((address_space(3))) unsigned int*)l, 16, 0, 0);
}

// ---------------- cast fp32 -> bf16 (8 elems/thread) ----------------
__global__ void cast_bf16_kernel(const float* __restrict__ in, bf16_t* __restrict__ out, int n)
{
    const int i = (blockIdx.x * 256 + threadIdx.x) * 8;
    if (i >= n) return;
    float4 a = *(const float4*)(in + i);
    float4 b = *(const float4*)(in + i + 4);
    bf16x8 o;
    o[0] = (bf16_t)a.x; o[1] = (bf16_t)a.y; o[2] = (bf16_t)a.z; o[3] = (bf16_t)a.w;
    o[4] = (bf16_t)b.x; o[5] = (bf16_t)b.y; o[6] = (bf16_t)b.z; o[7] = (bf16_t)b.w;
    *(bf16x8*)(out + i) = o;
}

// ---------------- 4x W[e][k][n] fp32 -> Wt[which][e][n][k] bf16 (fused) ----------------
__global__ void wtrans4_kernel(const float* __restrict__ W0, const float* __restrict__ W1,
                               const float* __restrict__ W2, const float* __restrict__ W3,
                               bf16_t* __restrict__ Wt)
{
    __shared__ float tile[32][33];
    const int z = blockIdx.z, which = z / NE, e = z - which * NE;
    const float* W = which == 0 ? W0 : which == 1 ? W1 : which == 2 ? W2 : W3;
    const int n0 = blockIdx.x * 32, k0 = blockIdx.y * 32;
    const int tx = threadIdx.x & 31, ty = threadIdx.x >> 5; // ty 0..7
    const float* Wp = W + ((size_t)e * DM + k0) * DM + n0;
#pragma unroll
    for (int r = 0; r < 32; r += 8) tile[ty + r][tx] = Wp[(size_t)(ty + r) * DM + tx];
    __syncthreads();
    bf16_t* Op = Wt + (((size_t)which * NE + e) * DM + n0) * DM + k0;
#pragma unroll
    for (int r = 0; r < 32; r += 8) Op[(size_t)(ty + r) * DM + tx] = (bf16_t)tile[tx][ty + r];
}

// ---------------- top-k gate selection + renorm (fp32, matches lax.top_k ties) ----------
__device__ __forceinline__ void topk_write(const float* p, const float* __restrict__ gb,
                                           float* __restrict__ G, int t)
{
    float l[NE], ex[NE];
    float mx = -3.4e38f;
#pragma unroll
    for (int e = 0; e < NE; e++) { l[e] = p[e] + gb[e]; mx = fmaxf(mx, l[e]); }
#pragma unroll
    for (int e = 0; e < NE; e++) ex[e] = __expf(l[e] - mx);
    bool sel[NE];
#pragma unroll
    for (int e = 0; e < NE; e++) sel[e] = false;
    float ssel = 0.f;
    for (int j = 0; j < 5; j++) {
        int bi = 0; float bv = -3.4e38f;
        for (int e = 0; e < NE; e++)
            if (!sel[e] && l[e] > bv) { bv = l[e]; bi = e; }
        sel[bi] = true; ssel += ex[bi];
    }
    const float inv = 1.f / ssel;
    for (int e = 0; e < NE; e++) G[(size_t)t * NE + e] = sel[e] ? ex[e] * inv : 0.f;
}

// one 64-thread block per token
__global__ void moe_gates(const float* __restrict__ X, const float* __restrict__ gw,
                          const float* __restrict__ gb, float* __restrict__ G)
{
    const int t = blockIdx.x;
    const int lane = threadIdx.x;
    const float* x = X + (size_t)t * DM;
    float p[NE];
#pragma unroll
    for (int e = 0; e < NE; e++) p[e] = 0.f;
    for (int i = lane; i < DM; i += 64) {
        const float xv = x[i];
        const float* g = gw + (size_t)i * NE;
#pragma unroll
        for (int e = 0; e < NE; e++) p[e] += xv * g[e];
    }
#pragma unroll
    for (int off = 32; off > 0; off >>= 1)
#pragma unroll
        for (int e = 0; e < NE; e++) p[e] += __shfl_down(p[e], off);
    if (lane == 0) topk_write(p, gb, G, t);
}

// fused k+v gates: 4 waves/block, one token per wave, X read once
__global__ void moe_gates_kv(const float* __restrict__ X,
                             const float* __restrict__ kgw, const float* __restrict__ kgb,
                             const float* __restrict__ vgw, const float* __restrict__ vgb,
                             float* __restrict__ Gk, float* __restrict__ Gv)
{
    const int t = blockIdx.x * 4 + (threadIdx.x >> 6);
    const int lane = threadIdx.x & 63;
    const float* x = X + (size_t)t * DM;
    float xr[8];
    *(float4*)&xr[0] = *(const float4*)(x + lane * 8);
    *(float4*)&xr[4] = *(const float4*)(x + lane * 8 + 4);
    float pk[NE], pv[NE];
#pragma unroll
    for (int e = 0; e < NE; e++) { pk[e] = 0.f; pv[e] = 0.f; }
#pragma unroll
    for (int j = 0; j < 8; j++) {
        const int i = lane * 8 + j;
        const float* gk = kgw + (size_t)i * NE;
        const float* gv = vgw + (size_t)i * NE;
#pragma unroll
        for (int e = 0; e < NE; e++) { pk[e] += xr[j] * gk[e]; pv[e] += xr[j] * gv[e]; }
    }
#pragma unroll
    for (int off = 32; off > 0; off >>= 1)
#pragma unroll
        for (int e = 0; e < NE; e++) { pk[e] += __shfl_down(pk[e], off); pv[e] += __shfl_down(pv[e], off); }
    if (lane == 0) { topk_write(pk, kgb, Gk, t); topk_write(pv, vgb, Gv, t); }
}

// ---------------- out[t,n] = sum_e g[t,e]*b[e,n]  (bias pre-init for atomic GEMMs) ------
__global__ void gate_bias_init(const float* __restrict__ G, const float* __restrict__ b,
                               float* __restrict__ out)
{
    const int idx = blockIdx.x * 256 + threadIdx.x;
    const int t = idx >> 9, n = idx & 511;
    const float* g = G + (size_t)t * NE;
    float s = 0.f;
#pragma unroll
    for (int e = 0; e < NE; e++) s += g[e] * b[e * DM + n];
    out[idx] = s;
}

// ---------------- fused k+v MoE GEMM: 128x128 tile, BK=64, async swizzled staging -------
// Block's n-half selects (Wk,Gk,k_b,kp) vs (Wv,Gv,v_b,vpT-transposed). 32 MFMA/iter.
__global__ __launch_bounds__(256, 2)
void moe_gemm_kv(const bf16_t* __restrict__ X,
                 const bf16_t* __restrict__ Wk, const bf16_t* __restrict__ Wv,
                 const float* __restrict__ kb, const float* __restrict__ vb,
                 const float* __restrict__ Gk, const float* __restrict__ Gv,
                 bf16_t* __restrict__ kp, bf16_t* __restrict__ vpT)
{
    constexpr int BM = 128, BN = 128, BK = 64;
    __shared__ bf16_t As[BM * BK];
    __shared__ bf16_t Bs[BN * BK];
    __shared__ float Gs[BM][NE];
    __shared__ float BiasS[NE][BN];

    const int tid = threadIdx.x, lane = tid & 63, w = tid >> 6;
    const int wr = w >> 1, wc = w & 1;
    const int l15 = lane & 15, quad = lane >> 4;
    const int m0 = blockIdx.x * BM;
    const int side = blockIdx.y >> 2;            // 0:k 1:v
    const int n0 = (blockIdx.y & 3) * BN;
    const bf16_t* Wt = side ? Wv : Wk;
    const float* G = side ? Gv : Gk;
    const float* bias = side ? vb : kb;

    for (int i = tid; i < BM * NE; i += 256) {
        int r = i / NE, e = i - r * NE;
        Gs[r][e] = G[(size_t)(m0 + r) * NE + e];
    }
    for (int i = tid; i < NE * BN; i += 256) {
        int e = i / BN, j = i - e * BN;
        BiasS[e][j] = bias[(size_t)e * DM + n0 + j];
    }

    const int rsub = lane >> 3, pch = lane & 7, csw = pch ^ rsub;
    const bf16_t* aptr[4]; bf16_t* alds[4]; bf16_t* blds[4];
#pragma unroll
    for (int j = 0; j < 4; j++) {
        const int rb = w * 32 + j * 8;
        aptr[j] = X + (size_t)(m0 + rb + rsub) * DM + csw * 8;
        alds[j] = (bf16_t*)As + rb * BK;
        blds[j] = (bf16_t*)Bs + rb * BK;
    }
    int amr[4], bnr[4];
#pragma unroll
    for (int f = 0; f < 4; f++) { amr[f] = wr * 64 + f * 16 + l15; bnr[f] = wc * 64 + f * 16 + l15; }

    const f32x4 zv = {0.f, 0.f, 0.f, 0.f};
    f32x4 acc[4][4];
#pragma unroll
    for (int a = 0; a < 4; a++)
#pragma unroll
        for (int c = 0; c < 4; c++) acc[a][c] = zv;

    for (int e = 0; e < NE; e++) {
        const bf16_t* bbase = Wt + ((size_t)e * DM + n0 + w * 32 + rsub) * DM + csw * 8;
        f32x4 acc2[4][4];
#pragma unroll
        for (int a = 0; a < 4; a++)
#pragma unroll
            for (int c = 0; c < 4; c++) acc2[a][c] = zv;

        for (int kt = 0; kt < 8; kt++) {
            __syncthreads();
#pragma unroll
            for (int j = 0; j < 4; j++) gl16(aptr[j] + kt * BK, alds[j]);
#pragma unroll
            for (int j = 0; j < 4; j++) gl16(bbase + (size_t)j * 8 * DM + kt * BK, blds[j]);
            __syncthreads();
#pragma unroll
            for (int kss = 0; kss < 2; kss++) {
                bf16x8 af[4], bf[4];
#pragma unroll
                for (int f = 0; f < 4; f++) {
                    af[f] = *(const bf16x8*)(As + amr[f] * BK + (((kss << 2) | quad) ^ (amr[f] & 7)) * 8);
                    bf[f] = *(const bf16x8*)(Bs + bnr[f] * BK + (((kss << 2) | quad) ^ (bnr[f] & 7)) * 8);
                }
#pragma unroll
                for (int mf = 0; mf < 4; mf++)
#pragma unroll
                    for (int nf = 0; nf < 4; nf++)
                        acc2[mf][nf] = __builtin_amdgcn_mfma_f32_16x16x32_bf16(
                            af[mf], bf[nf], acc2[mf][nf], 0, 0, 0);
            }
        }
#pragma unroll
        for (int mf = 0; mf < 4; mf++)
#pragma unroll
            for (int r = 0; r < 4; r++) {
                const float g = Gs[wr * 64 + mf * 16 + quad * 4 + r][e];
#pragma unroll
                for (int nf = 0; nf < 4; nf++) acc[mf][nf][r] += g * acc2[mf][nf][r];
            }
    }

#pragma unroll
    for (int mf = 0; mf < 4; mf++) {
#pragma unroll
        for (int nf = 0; nf < 4; nf++) {
            const int n = wc * 64 + nf * 16 + l15;
            float vals[4];
#pragma unroll
            for (int r = 0; r < 4; r++) {
                const int m = wr * 64 + mf * 16 + quad * 4 + r;
                float v = acc[mf][nf][r];
#pragma unroll
                for (int e = 0; e < NE; e++) v += Gs[m][e] * BiasS[e][n];
                vals[r] = v;
            }
            if (side) {   // vpT: [b][dim 512][tok 4096], 4 consecutive tokens packed
                const int mg = m0 + wr * 64 + mf * 16 + quad * 4;
                const int b = mg >> 12, t = mg & 4095;
                bf16x4 pk;
                pk[0] = (bf16_t)vals[0]; pk[1] = (bf16_t)vals[1];
                pk[2] = (bf16_t)vals[2]; pk[3] = (bf16_t)vals[3];
                *(bf16x4*)(vpT + ((size_t)(b * DM) + n0 + n) * 4096 + t) = pk;
            } else {
#pragma unroll
                for (int r = 0; r < 4; r++) {
                    const int m = wr * 64 + mf * 16 + quad * 4 + r;
                    kp[(size_t)(m0 + m) * DM + n0 + n] = (bf16_t)vals[r];
                }
            }
        }
    }
}

// ---------------- expert-split MoE GEMM (small M): 2 experts/block, fp32 atomic out -----
// Bias handled by gate_bias_init. Grid (M/64, 512/64, 5).
__global__ __launch_bounds__(256, 4)
void moe_gemm_split(const bf16_t* __restrict__ X, const bf16_t* __restrict__ Wt,
                    const float* __restrict__ G, float* __restrict__ out)
{
    constexpr int BK = 64;
    __shared__ bf16_t As[64 * BK];
    __shared__ bf16_t Bs[64 * BK];
    __shared__ float Gs[64][2];
    const int tid = threadIdx.x, lane = tid & 63, w = tid >> 6;
    const int wr = w >> 1, wc = w & 1;
    const int l15 = lane & 15, quad = lane >> 4;
    const int m0 = blockIdx.x * 64, n0 = blockIdx.y * 64, e0 = blockIdx.z * 2;

    if (tid < 128) {
        int r = tid >> 1, e = tid & 1;
        Gs[r][e] = G[(size_t)(m0 + r) * NE + e0 + e];
    }

    const int rsub = lane >> 3, pch = lane & 7, csw = pch ^ rsub;
    const bf16_t* aptr[2]; bf16_t* alds[2]; bf16_t* blds[2];
#pragma unroll
    for (int j = 0; j < 2; j++) {
        const int rb = w * 16 + j * 8;
        aptr[j] = X + (size_t)(m0 + rb + rsub) * DM + csw * 8;
        alds[j] = (bf16_t*)As + rb * BK;
        blds[j] = (bf16_t*)Bs + rb * BK;
    }
    const int amr[2] = {wr * 32 + l15, wr * 32 + 16 + l15};
    const int bnr[2] = {wc * 32 + l15, wc * 32 + 16 + l15};

    const f32x4 zv = {0.f, 0.f, 0.f, 0.f};
    f32x4 acc[2][2];
#pragma unroll
    for (int a = 0; a < 2; a++)
#pragma unroll
        for (int c = 0; c < 2; c++) acc[a][c] = zv;

#pragma unroll
    for (int ee = 0; ee < 2; ee++) {
        const int e = e0 + ee;
        const bf16_t* bbase = Wt + ((size_t)e * DM + n0 + w * 16 + rsub) * DM + csw * 8;
        f32x4 acc2[2][2];
#pragma unroll
        for (int a = 0; a < 2; a++)
#pragma unroll
            for (int c = 0; c < 2; c++) acc2[a][c] = zv;
        for (int kt = 0; kt < 8; kt++) {
            __syncthreads();
#pragma unroll
            for (int j = 0; j < 2; j++) gl16(aptr[j] + kt * BK, alds[j]);
#pragma unroll
            for (int j = 0; j < 2; j++) gl16(bbase + (size_t)j * 8 * DM + kt * BK, blds[j]);
            __syncthreads();
#pragma unroll
            for (int kss = 0; kss < 2; kss++) {
                bf16x8 af[2], bf[2];
#pragma unroll
                for (int f = 0; f < 2; f++) {
                    af[f] = *(const bf16x8*)(As + amr[f] * BK + (((kss << 2) | quad) ^ (amr[f] & 7)) * 8);
                    bf[f] = *(const bf16x8*)(Bs + bnr[f] * BK + (((kss << 2) | quad) ^ (bnr[f] & 7)) * 8);
                }
#pragma unroll
                for (int mf = 0; mf < 2; mf++)
#pragma unroll
                    for (int nf = 0; nf < 2; nf++)
                        acc2[mf][nf] = __builtin_amdgcn_mfma_f32_16x16x32_bf16(
                            af[mf], bf[nf], acc2[mf][nf], 0, 0, 0);
            }
        }
#pragma unroll
        for (int mf = 0; mf < 2; mf++)
#pragma unroll
            for (int r = 0; r < 4; r++) {
                const float g = Gs[wr * 32 + mf * 16 + quad * 4 + r][ee];
#pragma unroll
                for (int nf = 0; nf < 2; nf++) acc[mf][nf][r] += g * acc2[mf][nf][r];
            }
    }
#pragma unroll
    for (int mf = 0; mf < 2; mf++)
#pragma unroll
        for (int nf = 0; nf < 2; nf++) {
            const int n = n0 + wc * 32 + nf * 16 + l15;
#pragma unroll
            for (int r = 0; r < 4; r++) {
                const int m = m0 + wr * 32 + mf * 16 + quad * 4 + r;
                atomicAdd(&out[(size_t)m * DM + n], acc[mf][nf][r]);
            }
        }
}

// ---------------- attention pass 1: online (m,l) stats per row, K-split 4 ----------------
__global__ __launch_bounds__(256, 2)
void attn_pass1(const float* __restrict__ qp, const bf16_t* __restrict__ kp,
                float* __restrict__ mws, float* __restrict__ lws)
{
    __shared__ bf16_t Qs[64][72];
    __shared__ bf16_t Ks[64 * 64];
    const int ksp = blockIdx.x, qt = blockIdx.y, bh = blockIdx.z;
    const int b = bh >> 3, h = bh & 7, q0 = qt * 64;
    const int tid = threadIdx.x, lane = tid & 63, w = tid >> 6;
    const int l15 = lane & 15, quad = lane >> 4;

    {   // stage Q * SCALE -> bf16 (qp is fp32)
        const int row = tid >> 2, cg = (tid & 3) * 16;
        const float* qs = qp + ((size_t)(b * 512 + q0 + row)) * DM + h * 64 + cg;
        float4 f[4];
#pragma unroll
        for (int j = 0; j < 4; j++) f[j] = *(const float4*)(qs + j * 4);
        bf16x8 o0, o1;
        o0[0]=(bf16_t)(f[0].x*SCALE_F); o0[1]=(bf16_t)(f[0].y*SCALE_F); o0[2]=(bf16_t)(f[0].z*SCALE_F); o0[3]=(bf16_t)(f[0].w*SCALE_F);
        o0[4]=(bf16_t)(f[1].x*SCALE_F); o0[5]=(bf16_t)(f[1].y*SCALE_F); o0[6]=(bf16_t)(f[1].z*SCALE_F); o0[7]=(bf16_t)(f[1].w*SCALE_F);
        o1[0]=(bf16_t)(f[2].x*SCALE_F); o1[1]=(bf16_t)(f[2].y*SCALE_F); o1[2]=(bf16_t)(f[2].z*SCALE_F); o1[3]=(bf16_t)(f[2].w*SCALE_F);
        o1[4]=(bf16_t)(f[3].x*SCALE_F); o1[5]=(bf16_t)(f[3].y*SCALE_F); o1[6]=(bf16_t)(f[3].z*SCALE_F); o1[7]=(bf16_t)(f[3].w*SCALE_F);
        *(bf16x8*)&Qs[row][cg] = o0;
        *(bf16x8*)&Qs[row][cg + 8] = o1;
    }
    const int rsub = lane >> 3, pch = lane & 7, csw = pch ^ rsub;
    const bf16_t* kptr[2]; bf16_t* klds[2];
#pragma unroll
    for (int j = 0; j < 2; j++) {
        const int rb = w * 16 + j * 8;
        kptr[j] = kp + ((size_t)(b * 4096 + rb + rsub)) * DM + h * 64 + csw * 8;
        klds[j] = (bf16_t*)Ks + rb * 64;
    }
    float mrun[4], lrun[4];
#pragma unroll
    for (int r = 0; r < 4; r++) { mrun[r] = -3.0e38f; lrun[r] = 0.f; }

    for (int kt = 0; kt < 16; kt++) {
        const size_t koff = (size_t)(ksp * 16 + kt) * 64 * DM;
        __syncthreads();
        gl16(kptr[0] + koff, klds[0]);
        gl16(kptr[1] + koff, klds[1]);
        __syncthreads();
        const f32x4 zv = {0.f, 0.f, 0.f, 0.f};
        f32x4 sacc[4] = {zv, zv, zv, zv};
#pragma unroll
        for (int kss = 0; kss < 2; kss++) {
            bf16x8 af = *(const bf16x8*)&Qs[w * 16 + l15][kss * 32 + quad * 8];
#pragma unroll
            for (int nf = 0; nf < 4; nf++) {
                const int br = nf * 16 + l15;
                bf16x8 bf = *(const bf16x8*)(Ks + br * 64 + (((kss << 2) | quad) ^ (br & 7)) * 8);
                sacc[nf] = __builtin_amdgcn_mfma_f32_16x16x32_bf16(af, bf, sacc[nf], 0, 0, 0);
            }
        }
#pragma unroll
        for (int r = 0; r < 4; r++) {
            float tm = fmaxf(fmaxf(sacc[0][r], sacc[1][r]), fmaxf(sacc[2][r], sacc[3][r]));
#pragma unroll
            for (int off = 1; off < 16; off <<= 1) tm = fmaxf(tm, __shfl_xor(tm, off));
            const float mn = fmaxf(mrun[r], tm);
            float s = __expf(sacc[0][r] - mn) + __expf(sacc[1][r] - mn) +
                      __expf(sacc[2][r] - mn) + __expf(sacc[3][r] - mn);
#pragma unroll
            for (int off = 1; off < 16; off <<= 1) s += __shfl_xor(s, off);
            lrun[r] = lrun[r] * __expf(mrun[r] - mn) + s;
            mrun[r] = mn;
        }
    }
    if (l15 == 0) {
#pragma unroll
        for (int r = 0; r < 4; r++) {
            const int row = q0 + w * 16 + quad * 4 + r;
            mws[((size_t)ksp * 16 + bh) * 512 + row] = mrun[r];
            lws[((size_t)ksp * 16 + bh) * 512 + row] = lrun[r];
        }
    }
}

// ---------------- attention pass 2: recompute S, write P to d_out, fused PV -------------
__global__ __launch_bounds__(256, 2)
void attn_pass2(const float* __restrict__ qp, const bf16_t* __restrict__ kp,
                const bf16_t* __restrict__ vpT, const float* __restrict__ mws,
                const float* __restrict__ lws, float* __restrict__ attn,
                float* __restrict__ xout)
{
    __shared__ bf16_t Qs[64][72];
    __shared__ bf16_t Ks[64 * 64];
    __shared__ bf16_t Vs[64 * 64];
    __shared__ bf16_t Ps[64][72];
    const int ksp = blockIdx.x, qt = blockIdx.y, bh = blockIdx.z;
    const int b = bh >> 3, h = bh & 7, q0 = qt * 64;
    const int tid = threadIdx.x, lane = tid & 63, w = tid >> 6;
    const int l15 = lane & 15, quad = lane >> 4;

    {   // stage Q * SCALE
        const int row = tid >> 2, cg = (tid & 3) * 16;
        const float* qs = qp + ((size_t)(b * 512 + q0 + row)) * DM + h * 64 + cg;
        float4 f[4];
#pragma unroll
        for (int j = 0; j < 4; j++) f[j] = *(const float4*)(qs + j * 4);
        bf16x8 o0, o1;
        o0[0]=(bf16_t)(f[0].x*SCALE_F); o0[1]=(bf16_t)(f[0].y*SCALE_F); o0[2]=(bf16_t)(f[0].z*SCALE_F); o0[3]=(bf16_t)(f[0].w*SCALE_F);
        o0[4]=(bf16_t)(f[1].x*SCALE_F); o0[5]=(bf16_t)(f[1].y*SCALE_F); o0[6]=(bf16_t)(f[1].z*SCALE_F); o0[7]=(bf16_t)(f[1].w*SCALE_F);
        o1[0]=(bf16_t)(f[2].x*SCALE_F); o1[1]=(bf16_t)(f[2].y*SCALE_F); o1[2]=(bf16_t)(f[2].z*SCALE_F); o1[3]=(bf16_t)(f[2].w*SCALE_F);
        o1[4]=(bf16_t)(f[3].x*SCALE_F); o1[5]=(bf16_t)(f[3].y*SCALE_F); o1[6]=(bf16_t)(f[3].z*SCALE_F); o1[7]=(bf16_t)(f[3].w*SCALE_F);
        *(bf16x8*)&Qs[row][cg] = o0;
        *(bf16x8*)&Qs[row][cg + 8] = o1;
    }
    // combined stats for my 4 rows
    float mrow[4], linv[4];
#pragma unroll
    for (int r = 0; r < 4; r++) {
        const int row = q0 + w * 16 + quad * 4 + r;
        float mv[4], lv[4], mm = -3.0e38f;
#pragma unroll
        for (int p = 0; p < 4; p++) {
            mv[p] = mws[((size_t)p * 16 + bh) * 512 + row];
            lv[p] = lws[((size_t)p * 16 + bh) * 512 + row];
            mm = fmaxf(mm, mv[p]);
        }
        float ll = 0.f;
#pragma unroll
        for (int p = 0; p < 4; p++) ll += lv[p] * __expf(mv[p] - mm);
        mrow[r] = mm; linv[r] = 1.f / ll;
    }
    const int rsub = lane >> 3, pch = lane & 7, csw = pch ^ rsub;
    const bf16_t* kptr[2]; const bf16_t* vptr[2]; bf16_t* klds[2]; bf16_t* vlds[2];
#pragma unroll
    for (int j = 0; j < 2; j++) {
        const int rb = w * 16 + j * 8;
        kptr[j] = kp + ((size_t)(b * 4096 + rb + rsub)) * DM + h * 64 + csw * 8;
        vptr[j] = vpT + ((size_t)(b * DM + h * 64 + rb + rsub)) * 4096 + csw * 8;
        klds[j] = (bf16_t*)Ks + rb * 64;
        vlds[j] = (bf16_t*)Vs + rb * 64;
    }
    const f32x4 zv = {0.f, 0.f, 0.f, 0.f};
    f32x4 oacc[4] = {zv, zv, zv, zv};
    float* ap = attn + ((size_t)bh * 512) * 4096;

    for (int kt = 0; kt < 16; kt++) {
        const int kg = (ksp * 16 + kt) * 64;
        __syncthreads();
        gl16(kptr[0] + (size_t)kg * DM, klds[0]);
        gl16(kptr[1] + (size_t)kg * DM, klds[1]);
        gl16(vptr[0] + kg, vlds[0]);
        gl16(vptr[1] + kg, vlds[1]);
        __syncthreads();
        f32x4 sacc[4] = {zv, zv, zv, zv};
#pragma unroll
        for (int kss = 0; kss < 2; kss++) {
            bf16x8 af = *(const bf16x8*)&Qs[w * 16 + l15][kss * 32 + quad * 8];
#pragma unroll
            for (int nf = 0; nf < 4; nf++) {
                const int br = nf * 16 + l15;
                bf16x8 bf = *(const bf16x8*)(Ks + br * 64 + (((kss << 2) | quad) ^ (br & 7)) * 8);
                sacc[nf] = __builtin_amdgcn_mfma_f32_16x16x32_bf16(af, bf, sacc[nf], 0, 0, 0);
            }
        }
#pragma unroll
        for (int nf = 0; nf < 4; nf++)
#pragma unroll
            for (int r = 0; r < 4; r++) {
                const float p = __expf(sacc[nf][r] - mrow[r]) * linv[r];
                ap[((size_t)(q0 + w * 16 + quad * 4 + r)) * 4096 + kg + nf * 16 + l15] = p;
                Ps[w * 16 + quad * 4 + r][nf * 16 + l15] = (bf16_t)p;
            }
        __syncthreads();
#pragma unroll
        for (int kss = 0; kss < 2; kss++) {
            bf16x8 paf = *(const bf16x8*)&Ps[w * 16 + l15][kss * 32 + quad * 8];
#pragma unroll
            for (int nf = 0; nf < 4; nf++) {
                const int br = nf * 16 + l15;
                bf16x8 vb = *(const bf16x8*)(Vs + br * 64 + (((kss << 2) | quad) ^ (br & 7)) * 8);
                oacc[nf] = __builtin_amdgcn_mfma_f32_16x16x32_bf16(paf, vb, oacc[nf], 0, 0, 0);
            }
        }
    }
#pragma unroll
    for (int nf = 0; nf < 4; nf++) {
        const int n = h * 64 + nf * 16 + l15;
#pragma unroll
        for (int r = 0; r < 4; r++) {
            const int m = b * 512 + q0 + w * 16 + quad * 4 + r;
            atomicAdd(&xout[(size_t)m * DM + n], oacc[nf][r]);
        }
    }
}

// ---------------- host ----------------
extern "C" void kernel_launch(void* const* d_in, const int* in_sizes, int n_in,
                              void* d_out, int out_size, void* d_ws, size_t ws_size,
                              hipStream_t stream)
{
    (void)in_sizes; (void)n_in; (void)out_size; (void)ws_size;
    const float* q    = (const float*)d_in[0];
    const float* kv   = (const float*)d_in[1];
    const float* q_gw = (const float*)d_in[2];
    const float* q_gb = (const float*)d_in[3];
    const float* q_w  = (const float*)d_in[4];
    const float* q_b  = (const float*)d_in[5];
    const float* k_gw = (const float*)d_in[6];
    const float* k_gb = (const float*)d_in[7];
    const float* k_w  = (const float*)d_in[8];
    const float* k_b  = (const float*)d_in[9];
    const float* v_gw = (const float*)d_in[10];
    const float* v_gb = (const float*)d_in[11];
    const float* v_w  = (const float*)d_in[12];
    const float* v_b  = (const float*)d_in[13];
    const float* o_gw = (const float*)d_in[14];
    const float* o_gb = (const float*)d_in[15];
    const float* o_w  = (const float*)d_in[16];
    const float* o_b  = (const float*)d_in[17];

    float* out0 = (float*)d_out;
    float* attn = out0 + (size_t)1024 * 512;

    char* ws = (char*)d_ws;
    size_t off = 0;
    auto alloc = [&](size_t bytes) {
        void* p = ws + off;
        off += (bytes + 255) & ~(size_t)255;
        return p;
    };
    bf16_t* Xq    = (bf16_t*)alloc((size_t)1024 * 512 * 2);
    bf16_t* Xkv   = (bf16_t*)alloc((size_t)8192 * 512 * 2);
    bf16_t* Wall  = (bf16_t*)alloc((size_t)4 * NE * 512 * 512 * 2);
    bf16_t* Wq_t  = Wall;
    bf16_t* Wk_t  = Wall + (size_t)1 * NE * 512 * 512;
    bf16_t* Wv_t  = Wall + (size_t)2 * NE * 512 * 512;
    bf16_t* Wo_t  = Wall + (size_t)3 * NE * 512 * 512;
    float*  qpf   = (float*)alloc((size_t)1024 * 512 * 4);   // q-proj fp32 (atomic)
    bf16_t* kp    = (bf16_t*)alloc((size_t)8192 * 512 * 2);
    bf16_t* vpT   = (bf16_t*)alloc((size_t)8192 * 512 * 2);
    float*  xatt  = (float*)alloc((size_t)1024 * 512 * 4);
    bf16_t* xbf   = (bf16_t*)alloc((size_t)1024 * 512 * 2);
    float*  Gq    = (float*)alloc((size_t)1024 * NE * 4);
    float*  Gk    = (float*)alloc((size_t)8192 * NE * 4);
    float*  Gv    = (float*)alloc((size_t)8192 * NE * 4);
    float*  Go    = (float*)alloc((size_t)1024 * NE * 4);
    float*  mws   = (float*)alloc((size_t)4 * 16 * 512 * 4);
    float*  lws   = (float*)alloc((size_t)4 * 16 * 512 * 4);

    cast_bf16_kernel<<<256, 256, 0, stream>>>(q, Xq, 1024 * 512);
    cast_bf16_kernel<<<2048, 256, 0, stream>>>(kv, Xkv, 8192 * 512);
    wtrans4_kernel<<<dim3(16, 16, 4 * NE), 256, 0, stream>>>(q_w, k_w, v_w, o_w, Wall);
    moe_gates<<<1024, 64, 0, stream>>>(q, q_gw, q_gb, Gq);
    moe_gates_kv<<<2048, 256, 0, stream>>>(kv, k_gw, k_gb, v_gw, v_gb, Gk, Gv);

    gate_bias_init<<<2048, 256, 0, stream>>>(Gq, q_b, qpf);
    moe_gemm_split<<<dim3(16, 8, 5), 256, 0, stream>>>(Xq, Wq_t, Gq, qpf);
    moe_gemm_kv<<<dim3(64, 8), 256, 0, stream>>>(Xkv, Wk_t, Wv_t, k_b, v_b, Gk, Gv, kp, vpT);

    attn_pass1<<<dim3(4, 8, 16), 256, 0, stream>>>(qpf, kp, mws, lws);
    hipMemsetAsync(xatt, 0, (size_t)1024 * 512 * 4, stream);
    attn_pass2<<<dim3(4, 8, 16), 256, 0, stream>>>(qpf, kp, vpT, mws, lws, attn, xatt);

    moe_gates<<<1024, 64, 0, stream>>>(xatt, o_gw, o_gb, Go);
    cast_bf16_kernel<<<256, 256, 0, stream>>>(xatt, xbf, 1024 * 512);
    gate_bias_init<<<2048, 256, 0, stream>>>(Go, o_b, out0);
    moe_gemm_split<<<dim3(16, 8, 5), 256, 0, stream>>>(xbf, Wo_t, Go, out0);
}